// Round 3
// baseline (87.782 us; speedup 1.0000x reference)
//
#include <hip/hip_runtime.h>
#include <hip/hip_bf16.h>
#include <math.h>

// Problem: B=8, N=2048, DIN=DOUT=512, adj binary p=0.01
// out = tanh( D^-1/2 (A v I) D^-1/2 (X W) + b )
//
// Schedule:
//   K0 wt_kernel : W (fp32) -> WT bf16, WT[n][k]=W[k][n]          (~2 us)
//   K1 fused_k1  : blocks 0..511   = bf16 MFMA gemm  H = X @ W
//                  blocks 512..4607 = adjacency -> edge lists + dinv
//                  (gemm compute hides under the 134 MB adj stream)
//   K2 aggregate : wave-per-row sparse gather + bias + tanh -> out

#define NROWS 16384      // B*N
#define NCOLS 2048       // N
#define DF    512
#define CAP   64         // max edges/row (Binom(2048,0.01): mean ~21.5, P(>=64) ~ 0)

typedef __attribute__((ext_vector_type(8))) short bf16x8;   // 8 bf16 (4 VGPRs)
typedef __attribute__((ext_vector_type(4))) float f32x4;

typedef const void __attribute__((address_space(1))) gvoid_t;
typedef void __attribute__((address_space(3))) svoid_t;

// ---------------------------------------------------------------------------
// K0: W -> W^T in bf16 (64 blocks of 64x64 tiles)
// ---------------------------------------------------------------------------
__global__ __launch_bounds__(256) void wt_kernel(
    const float* __restrict__ W, __hip_bfloat16* __restrict__ WT) {
  __shared__ float t[64][65];
  const int b2 = blockIdx.x;
  const int bx = b2 & 7, by = b2 >> 3;
  const int tid = threadIdx.x;
  const int tx = tid & 63, ty = tid >> 6;
  #pragma unroll
  for (int i = 0; i < 16; ++i)
    t[ty + i * 4][tx] = W[(size_t)(by * 64 + ty + i * 4) * DF + bx * 64 + tx];
  __syncthreads();
  #pragma unroll
  for (int i = 0; i < 16; ++i)                     // WT[n][k] = W[k][n]
    WT[(size_t)(bx * 64 + ty + i * 4) * DF + by * 64 + tx] =
        __float2bfloat16(t[tx][ty + i * 4]);
}

// ---------------------------------------------------------------------------
// K1: heterogeneous. blocks [0,512): gemm 128x128 tile, BK=32, 4 waves 2x2.
//     A (X fp32) reg-staged -> bf16 -> LDS; B (WT bf16) via global_load_lds.
//     blocks [512,4608): edge extraction, one wave per adjacency row.
// ---------------------------------------------------------------------------
__global__ __launch_bounds__(256) void fused_k1(
    const float* __restrict__ X, const __hip_bfloat16* __restrict__ WT,
    const float* __restrict__ adj, __hip_bfloat16* __restrict__ H,
    int* __restrict__ cnt, int* __restrict__ edges, float* __restrict__ dinv) {
  __shared__ __hip_bfloat16 As[128 * 32];          // 8 KB  [row][k]
  __shared__ __hip_bfloat16 Bs[128 * 32];          // 8 KB  [n][k]
  const int id = blockIdx.x;
  const int tid = threadIdx.x;
  const int lane = tid & 63;
  const int w = tid >> 6;

  if (id < 512) {
    // ---- GEMM path ----
    // XCD mapping: all 4 N-blocks of one M-panel land on the same XCD
    // (assumes dispatch round-robin id%8 -> XCD; wrong mapping only costs BW)
    const int xcd = id & 7;
    const int jj = id >> 3;                        // 0..63
    const int p  = xcd * 16 + (jj >> 2);           // M-panel 0..127
    const int bm = p * 128;
    const int bn = (jj & 3) * 128;

    const int wm = (w >> 1) * 64;
    const int wn = (w & 1) * 64;
    const int srow = tid >> 2;                     // B staging row (0..63)
    const int scol = (tid & 3) * 8;
    const int arow = tid >> 1;                     // A staging row (0..127)
    const int akh  = (tid & 1) * 16;               // A staging k-half
    const int kl = (lane >> 4) * 8;
    const int rl = lane & 15;

    f32x4 acc[4][4] = {};

    for (int k0 = 0; k0 < DF; k0 += 32) {
      // B tile: direct-to-LDS DMA (dest = base + lane*16, linear)
      #pragma unroll
      for (int i = 0; i < 2; ++i) {
        const __hip_bfloat16* gb = WT + (size_t)(bn + i * 64 + srow) * DF + k0 + scol;
        char* lb = (char*)Bs + i * 4096 + w * 1024;
        __builtin_amdgcn_global_load_lds((gvoid_t*)gb, (svoid_t*)lb, 16, 0, 0);
      }
      // A tile: fp32 -> bf16 in registers -> LDS (lane writes 32B at tid*32)
      const float* gaf = X + (size_t)(bm + arow) * DF + k0 + akh;
      float xs[16];
      *(float4*)&xs[0]  = ((const float4*)gaf)[0];
      *(float4*)&xs[4]  = ((const float4*)gaf)[1];
      *(float4*)&xs[8]  = ((const float4*)gaf)[2];
      *(float4*)&xs[12] = ((const float4*)gaf)[3];
      union { __hip_bfloat16 h[16]; uint4 q[2]; } pk;
      #pragma unroll
      for (int i = 0; i < 16; ++i) pk.h[i] = __float2bfloat16(xs[i]);
      char* la = (char*)As + arow * 64 + akh * 2;
      ((uint4*)la)[0] = pk.q[0];
      ((uint4*)la)[1] = pk.q[1];

      __syncthreads();                             // drains vmcnt (DMA) + lgkm (ds_write)

      bf16x8 af[4], bf[4];
      #pragma unroll
      for (int mi = 0; mi < 4; ++mi)
        af[mi] = *(const bf16x8*)&As[(wm + mi * 16 + rl) * 32 + kl];
      #pragma unroll
      for (int ni = 0; ni < 4; ++ni)
        bf[ni] = *(const bf16x8*)&Bs[(wn + ni * 16 + rl) * 32 + kl];
      #pragma unroll
      for (int mi = 0; mi < 4; ++mi)
        #pragma unroll
        for (int ni = 0; ni < 4; ++ni)
          acc[mi][ni] = __builtin_amdgcn_mfma_f32_16x16x32_bf16(af[mi], bf[ni], acc[mi][ni], 0, 0, 0);
      __syncthreads();
    }

    // epilogue: D col=lane&15, row=(lane>>4)*4+j
    const int rq = (lane >> 4) * 4;
    #pragma unroll
    for (int mi = 0; mi < 4; ++mi)
      #pragma unroll
      for (int ni = 0; ni < 4; ++ni) {
        const int col = bn + wn + ni * 16 + rl;
        #pragma unroll
        for (int j = 0; j < 4; ++j) {
          const int row = bm + wm + mi * 16 + rq + j;
          H[(size_t)row * DF + col] = __float2bfloat16(acc[mi][ni][j]);
        }
      }
  } else {
    // ---- edge-extraction path ----
    const int r = (id - 512) * 4 + w;              // 0..16383
    const int n = r & (NCOLS - 1);
    const float4* row4 = (const float4*)(adj + (size_t)r * NCOLS);
    const unsigned long long lt = (1ull << lane) - 1ull;
    int base = 0;
    #pragma unroll
    for (int k = 0; k < NCOLS / 256; ++k) {        // 8 iterations
      const float4 v = row4[k * 64 + lane];
      const int c0 = k * 256 + lane * 4;
      const bool f0 = (v.x != 0.0f) || (c0 + 0 == n);
      const bool f1 = (v.y != 0.0f) || (c0 + 1 == n);
      const bool f2 = (v.z != 0.0f) || (c0 + 2 == n);
      const bool f3 = (v.w != 0.0f) || (c0 + 3 == n);
      const unsigned long long m0 = __ballot(f0);
      const unsigned long long m1 = __ballot(f1);
      const unsigned long long m2 = __ballot(f2);
      const unsigned long long m3 = __ballot(f3);
      const int n0 = __popcll(m0), n1 = __popcll(m1), n2 = __popcll(m2), n3 = __popcll(m3);
      if (f0) { int p = base + __popcll(m0 & lt);                if (p < CAP) edges[(size_t)r * CAP + p] = c0 + 0; }
      if (f1) { int p = base + n0 + __popcll(m1 & lt);           if (p < CAP) edges[(size_t)r * CAP + p] = c0 + 1; }
      if (f2) { int p = base + n0 + n1 + __popcll(m2 & lt);      if (p < CAP) edges[(size_t)r * CAP + p] = c0 + 2; }
      if (f3) { int p = base + n0 + n1 + n2 + __popcll(m3 & lt); if (p < CAP) edges[(size_t)r * CAP + p] = c0 + 3; }
      base += n0 + n1 + n2 + n3;
    }
    if (lane == 0) {
      cnt[r] = base < CAP ? base : CAP;
      dinv[r] = rsqrtf((float)base);               // deg >= 1 (forced self-loop)
    }
  }
}

// ---------------------------------------------------------------------------
// K2: wave-per-row gather. Lane l owns output elems l*8..l*8+7.
// Edge list in registers, broadcast via __shfl. Batch->XCD swizzle keeps each
// 2MB bf16 h-slice resident in its XCD's L2.
// ---------------------------------------------------------------------------
__global__ __launch_bounds__(256) void aggregate(
    const __hip_bfloat16* __restrict__ h, const int* __restrict__ cnt,
    const int* __restrict__ edges, const float* __restrict__ dinv,
    const float* __restrict__ bias, float* __restrict__ out) {
  const int lane = threadIdx.x & 63;
  const int wv = threadIdx.x >> 6;
  const int j = blockIdx.x * 4 + wv;
  const int r = (j & 7) * NCOLS + (j >> 3);        // bijective: batch = j%8 -> XCD j%8
  const int b = r >> 11;
  const int c = cnt[r];
  int   ml = 0;
  float wl = 0.0f;
  if (lane < c) {
    ml = edges[(size_t)r * CAP + lane];
    wl = dinv[(b << 11) + ml];
  }
  const float4* b4 = (const float4*)bias;
  const float4 bb0 = b4[lane * 2];
  const float4 bb1 = b4[lane * 2 + 1];

  float acc[8] = {0.f, 0.f, 0.f, 0.f, 0.f, 0.f, 0.f, 0.f};
  const uint4* hbase = (const uint4*)(h + ((size_t)(b << 11)) * DF);  // 64 uint4 per row
  for (int e = 0; e < c; ++e) {
    const int   m  = __shfl(ml, e);
    const float wt = __shfl(wl, e);
    const uint4 hv = hbase[(size_t)m * 64 + lane];
    acc[0] += wt * __uint_as_float(hv.x << 16);
    acc[1] += wt * __uint_as_float(hv.x & 0xffff0000u);
    acc[2] += wt * __uint_as_float(hv.y << 16);
    acc[3] += wt * __uint_as_float(hv.y & 0xffff0000u);
    acc[4] += wt * __uint_as_float(hv.z << 16);
    acc[5] += wt * __uint_as_float(hv.z & 0xffff0000u);
    acc[6] += wt * __uint_as_float(hv.w << 16);
    acc[7] += wt * __uint_as_float(hv.w & 0xffff0000u);
  }
  const float dn = dinv[r];
  float4 o0, o1;
  o0.x = tanhf(acc[0] * dn + bb0.x);
  o0.y = tanhf(acc[1] * dn + bb0.y);
  o0.z = tanhf(acc[2] * dn + bb0.z);
  o0.w = tanhf(acc[3] * dn + bb0.w);
  o1.x = tanhf(acc[4] * dn + bb1.x);
  o1.y = tanhf(acc[5] * dn + bb1.y);
  o1.z = tanhf(acc[6] * dn + bb1.z);
  o1.w = tanhf(acc[7] * dn + bb1.w);
  float4* op = (float4*)(out + (size_t)r * DF + lane * 8);
  op[0] = o0;
  op[1] = o1;
}

// ---------------------------------------------------------------------------
extern "C" void kernel_launch(void* const* d_in, const int* in_sizes, int n_in,
                              void* d_out, int out_size, void* d_ws, size_t ws_size,
                              hipStream_t stream) {
  const float* X    = (const float*)d_in[0];   // [8,2048,512]
  const float* adj  = (const float*)d_in[1];   // [8,2048,2048]
  const float* W    = (const float*)d_in[2];   // [512,512]
  const float* bias = (const float*)d_in[3];   // [512]
  float* out = (float*)d_out;

  char* ws = (char*)d_ws;
  __hip_bfloat16* h    = (__hip_bfloat16*)(ws);                    // 16,777,216 B
  __hip_bfloat16* WT   = (__hip_bfloat16*)(ws + 16777216);         //    524,288 B
  float*          dinv = (float*)(ws + 17301504);                  //     65,536 B
  int*            cnt  = (int*)  (ws + 17367040);                  //     65,536 B
  int*            edges= (int*)  (ws + 17432576);                  //  4,194,304 B
  // total ws: 21,626,880 B

  wt_kernel<<<64, 256, 0, stream>>>(W, WT);
  fused_k1<<<512 + NROWS / 4, 256, 0, stream>>>(X, WT, adj, h, cnt, edges, dinv);
  aggregate<<<NROWS / 4, 256, 0, stream>>>(h, cnt, edges, dinv, bias, out);
}

// Round 4
// 83.044 us; speedup vs baseline: 1.0571x; 1.0571x over previous
//
#include <hip/hip_runtime.h>
#include <hip/hip_bf16.h>
#include <math.h>

// Problem: B=8, N=2048, DIN=DOUT=512, adj binary p=0.01
// out = tanh( D^-1/2 (A v I) D^-1/2 (X W) + b )
//
// Schedule (3 graph-captured launches):
//   K1 prep      : blocks 0..63    = W (fp32) -> WT bf16 (WT[n][k]=W[k][n])
//                  blocks 64..4159 = adjacency -> edge lists + dinv (wave/row)
//   K2 gemm_k    : H = X @ W, bf16 MFMA, 128x128 tile, BK=32,
//                  double-buffered LDS, 1 barrier per K-step, A reg-staged
//   K3 aggregate : wave-per-row sparse gather + bias + tanh -> out

#define NROWS 16384      // B*N
#define NCOLS 2048       // N
#define DF    512
#define CAP   64         // max edges/row (Binom(2048,0.01): mean ~21.5, P(>=64) ~ 0)

typedef __attribute__((ext_vector_type(8))) short bf16x8;   // 8 bf16 (4 VGPRs)
typedef __attribute__((ext_vector_type(4))) float f32x4;

typedef const void __attribute__((address_space(1))) gvoid_t;
typedef void __attribute__((address_space(3))) svoid_t;

// ---------------------------------------------------------------------------
// K1: heterogeneous prep.
//   blocks [0,64)     : W -> W^T bf16, 64x64 tiles via LDS
//   blocks [64,4160)  : edge extraction, one wave per adjacency row.
//                       All 8 row-chunk loads issued before the ballot phase
//                       (8 KB in flight per wave -> HBM-saturating).
// ---------------------------------------------------------------------------
__global__ __launch_bounds__(256) void prep(
    const float* __restrict__ W, __hip_bfloat16* __restrict__ WT,
    const float* __restrict__ adj, int* __restrict__ cnt,
    int* __restrict__ edges, float* __restrict__ dinv) {
  __shared__ float t[64][65];
  const int id = blockIdx.x;
  const int tid = threadIdx.x;
  if (id < 64) {
    const int bx = id & 7, by = id >> 3;
    const int tx = tid & 63, ty = tid >> 6;
    #pragma unroll
    for (int i = 0; i < 16; ++i)
      t[ty + i * 4][tx] = W[(size_t)(by * 64 + ty + i * 4) * DF + bx * 64 + tx];
    __syncthreads();
    #pragma unroll
    for (int i = 0; i < 16; ++i)                   // WT[n][k] = W[k][n]
      WT[(size_t)(bx * 64 + ty + i * 4) * DF + by * 64 + tx] =
          __float2bfloat16(t[tx][ty + i * 4]);
    return;
  }
  const int lane = tid & 63;
  const int wv = tid >> 6;
  const int r = (id - 64) * 4 + wv;                // 0..16383
  const int n = r & (NCOLS - 1);
  const float4* row4 = (const float4*)(adj + (size_t)r * NCOLS);
  // phase 1: issue all 8 loads (8 KB/wave in flight)
  float4 v[8];
  #pragma unroll
  for (int k = 0; k < 8; ++k) v[k] = row4[k * 64 + lane];
  // phase 2: ballot compaction (deterministic j-major order)
  const unsigned long long lt = (1ull << lane) - 1ull;
  int base = 0;
  #pragma unroll
  for (int k = 0; k < 8; ++k) {
    const int c0 = k * 256 + lane * 4;
    const bool f0 = (v[k].x != 0.0f) || (c0 + 0 == n);
    const bool f1 = (v[k].y != 0.0f) || (c0 + 1 == n);
    const bool f2 = (v[k].z != 0.0f) || (c0 + 2 == n);
    const bool f3 = (v[k].w != 0.0f) || (c0 + 3 == n);
    const unsigned long long m0 = __ballot(f0);
    const unsigned long long m1 = __ballot(f1);
    const unsigned long long m2 = __ballot(f2);
    const unsigned long long m3 = __ballot(f3);
    const int n0 = __popcll(m0), n1 = __popcll(m1), n2 = __popcll(m2), n3 = __popcll(m3);
    if (f0) { int p = base + __popcll(m0 & lt);                if (p < CAP) edges[(size_t)r * CAP + p] = c0 + 0; }
    if (f1) { int p = base + n0 + __popcll(m1 & lt);           if (p < CAP) edges[(size_t)r * CAP + p] = c0 + 1; }
    if (f2) { int p = base + n0 + n1 + __popcll(m2 & lt);      if (p < CAP) edges[(size_t)r * CAP + p] = c0 + 2; }
    if (f3) { int p = base + n0 + n1 + n2 + __popcll(m3 & lt); if (p < CAP) edges[(size_t)r * CAP + p] = c0 + 3; }
    base += n0 + n1 + n2 + n3;
  }
  if (lane == 0) {
    cnt[r] = base < CAP ? base : CAP;
    dinv[r] = rsqrtf((float)base);                 // deg >= 1 (forced self-loop)
  }
}

// ---------------------------------------------------------------------------
// K2: H = X @ WT^T. 128x128 tile, BK=32, 4 waves (2x2), double-buffered LDS,
//     one barrier per K-step. B staged via global_load_lds DMA; A staged
//     fp32->bf16 through registers (loads issued one phase early, ds_write
//     after the MFMA block — T14 split).
// ---------------------------------------------------------------------------
__global__ __launch_bounds__(256) void gemm_k(
    const float* __restrict__ X, const __hip_bfloat16* __restrict__ WT,
    __hip_bfloat16* __restrict__ H) {
  __shared__ __hip_bfloat16 As[2][128 * 32];       // 2 x 8 KB  [row][k]
  __shared__ __hip_bfloat16 Bs[2][128 * 32];       // 2 x 8 KB  [n][k]
  const int tid = threadIdx.x;
  const int lane = tid & 63;
  const int w = tid >> 6;
  // XCD mapping: 4 N-blocks of one M-panel -> same XCD (L2 reuse of X tile)
  const int id = blockIdx.x;
  const int xcd = id & 7;
  const int jj = id >> 3;                          // 0..63
  const int bm = (xcd * 16 + (jj >> 2)) * 128;
  const int bn = (jj & 3) * 128;

  const int wm = (w >> 1) * 64;
  const int wn = (w & 1) * 64;
  const int srow = tid >> 2;                       // B staging row (0..63)
  const int scol = (tid & 3) * 8;
  const int arow = tid >> 1;                       // A staging row (0..127)
  const int akh  = (tid & 1) * 16;                 // A staging k-half
  const int kl = (lane >> 4) * 8;
  const int rl = lane & 15;

  f32x4 acc[4][4] = {};
  float4 ar0, ar1, ar2, ar3;                       // A prefetch regs

  #define LOAD_A(k0)  do {                                              \
    const float4* g = (const float4*)(X + (size_t)(bm + arow) * DF + (k0) + akh); \
    ar0 = g[0]; ar1 = g[1]; ar2 = g[2]; ar3 = g[3]; } while (0)

  #define STAGE_B(k0, buf)  do {                                        \
    _Pragma("unroll")                                                   \
    for (int i = 0; i < 2; ++i) {                                       \
      const __hip_bfloat16* gb = WT + (size_t)(bn + i * 64 + srow) * DF + (k0) + scol; \
      char* lb = (char*)&Bs[buf][0] + i * 4096 + w * 1024;              \
      __builtin_amdgcn_global_load_lds((gvoid_t*)gb, (svoid_t*)lb, 16, 0, 0); \
    } } while (0)

  #define WRITE_A(buf)  do {                                            \
    float xs[16];                                                       \
    *(float4*)&xs[0] = ar0; *(float4*)&xs[4] = ar1;                     \
    *(float4*)&xs[8] = ar2; *(float4*)&xs[12] = ar3;                    \
    union { __hip_bfloat16 h[16]; uint4 q[2]; } pk;                     \
    _Pragma("unroll")                                                   \
    for (int i = 0; i < 16; ++i) pk.h[i] = __float2bfloat16(xs[i]);     \
    char* la = (char*)&As[buf][0] + arow * 64 + akh * 2;                \
    ((uint4*)la)[0] = pk.q[0];                                          \
    ((uint4*)la)[1] = pk.q[1]; } while (0)

  // prologue: fill buffer 0
  LOAD_A(0);
  STAGE_B(0, 0);
  WRITE_A(0);
  __syncthreads();                                 // vmcnt(0)+lgkmcnt(0)+barrier

  for (int t = 0; t < 16; ++t) {
    const int cur = t & 1, nxt = cur ^ 1;
    if (t < 15) {
      LOAD_A((t + 1) * 32);                        // issue next-tile loads FIRST
      STAGE_B((t + 1) * 32, nxt);
    }
    bf16x8 af[4], bf[4];
    #pragma unroll
    for (int mi = 0; mi < 4; ++mi)
      af[mi] = *(const bf16x8*)&As[cur][(wm + mi * 16 + rl) * 32 + kl];
    #pragma unroll
    for (int ni = 0; ni < 4; ++ni)
      bf[ni] = *(const bf16x8*)&Bs[cur][(wn + ni * 16 + rl) * 32 + kl];
    #pragma unroll
    for (int mi = 0; mi < 4; ++mi)
      #pragma unroll
      for (int ni = 0; ni < 4; ++ni)
        acc[mi][ni] = __builtin_amdgcn_mfma_f32_16x16x32_bf16(af[mi], bf[ni], acc[mi][ni], 0, 0, 0);
    if (t < 15) WRITE_A(nxt);                      // convert + ds_write after MFMA
    __syncthreads();                               // one barrier per K-step
  }

  // epilogue: D col=lane&15, row=(lane>>4)*4+j
  const int rq = (lane >> 4) * 4;
  #pragma unroll
  for (int mi = 0; mi < 4; ++mi)
    #pragma unroll
    for (int ni = 0; ni < 4; ++ni) {
      const int col = bn + wn + ni * 16 + rl;
      #pragma unroll
      for (int j = 0; j < 4; ++j) {
        const int row = bm + wm + mi * 16 + rq + j;
        H[(size_t)row * DF + col] = __float2bfloat16(acc[mi][ni][j]);
      }
    }
  #undef LOAD_A
  #undef STAGE_B
  #undef WRITE_A
}

// ---------------------------------------------------------------------------
// K3: wave-per-row gather. Lane l owns output elems l*8..l*8+7.
// Edge list in registers, broadcast via __shfl. Batch->XCD swizzle keeps each
// 2MB bf16 h-slice resident in its XCD's L2.
// ---------------------------------------------------------------------------
__global__ __launch_bounds__(256) void aggregate(
    const __hip_bfloat16* __restrict__ h, const int* __restrict__ cnt,
    const int* __restrict__ edges, const float* __restrict__ dinv,
    const float* __restrict__ bias, float* __restrict__ out) {
  const int lane = threadIdx.x & 63;
  const int wv = threadIdx.x >> 6;
  const int j = blockIdx.x * 4 + wv;
  const int r = (j & 7) * NCOLS + (j >> 3);        // bijective: batch = j%8 -> XCD j%8
  const int b = r >> 11;
  const int c = cnt[r];
  int   ml = 0;
  float wl = 0.0f;
  if (lane < c) {
    ml = edges[(size_t)r * CAP + lane];
    wl = dinv[(b << 11) + ml];
  }
  const float4* b4 = (const float4*)bias;
  const float4 bb0 = b4[lane * 2];
  const float4 bb1 = b4[lane * 2 + 1];

  float acc[8] = {0.f, 0.f, 0.f, 0.f, 0.f, 0.f, 0.f, 0.f};
  const uint4* hbase = (const uint4*)(h + ((size_t)(b << 11)) * DF);  // 64 uint4 per row
  for (int e = 0; e < c; ++e) {
    const int   m  = __shfl(ml, e);
    const float wt = __shfl(wl, e);
    const uint4 hv = hbase[(size_t)m * 64 + lane];
    acc[0] += wt * __uint_as_float(hv.x << 16);
    acc[1] += wt * __uint_as_float(hv.x & 0xffff0000u);
    acc[2] += wt * __uint_as_float(hv.y << 16);
    acc[3] += wt * __uint_as_float(hv.y & 0xffff0000u);
    acc[4] += wt * __uint_as_float(hv.z << 16);
    acc[5] += wt * __uint_as_float(hv.z & 0xffff0000u);
    acc[6] += wt * __uint_as_float(hv.w << 16);
    acc[7] += wt * __uint_as_float(hv.w & 0xffff0000u);
  }
  const float dn = dinv[r];
  float4 o0, o1;
  o0.x = tanhf(acc[0] * dn + bb0.x);
  o0.y = tanhf(acc[1] * dn + bb0.y);
  o0.z = tanhf(acc[2] * dn + bb0.z);
  o0.w = tanhf(acc[3] * dn + bb0.w);
  o1.x = tanhf(acc[4] * dn + bb1.x);
  o1.y = tanhf(acc[5] * dn + bb1.y);
  o1.z = tanhf(acc[6] * dn + bb1.z);
  o1.w = tanhf(acc[7] * dn + bb1.w);
  float4* op = (float4*)(out + (size_t)r * DF + lane * 8);
  op[0] = o0;
  op[1] = o1;
}

// ---------------------------------------------------------------------------
extern "C" void kernel_launch(void* const* d_in, const int* in_sizes, int n_in,
                              void* d_out, int out_size, void* d_ws, size_t ws_size,
                              hipStream_t stream) {
  const float* X    = (const float*)d_in[0];   // [8,2048,512]
  const float* adj  = (const float*)d_in[1];   // [8,2048,2048]
  const float* W    = (const float*)d_in[2];   // [512,512]
  const float* bias = (const float*)d_in[3];   // [512]
  float* out = (float*)d_out;

  char* ws = (char*)d_ws;
  __hip_bfloat16* h    = (__hip_bfloat16*)(ws);                    // 16,777,216 B
  __hip_bfloat16* WT   = (__hip_bfloat16*)(ws + 16777216);         //    524,288 B
  float*          dinv = (float*)(ws + 17301504);                  //     65,536 B
  int*            cnt  = (int*)  (ws + 17367040);                  //     65,536 B
  int*            edges= (int*)  (ws + 17432576);                  //  4,194,304 B
  // total ws: 21,626,880 B

  prep<<<64 + NROWS / 4, 256, 0, stream>>>(W, WT, adj, cnt, edges, dinv);
  gemm_k<<<512, 256, 0, stream>>>(X, WT, h);
  aggregate<<<NROWS / 4, 256, 0, stream>>>(h, cnt, edges, dinv, bias, out);
}